// Round 1
// baseline (413.045 us; speedup 1.0000x reference)
//
#include <hip/hip_runtime.h>
#include <stdint.h>

typedef int v4i __attribute__((ext_vector_type(4)));

static constexpr int MDIM = 8192;   // B * S
static constexpr int NDIM = 4096;   // D_OUT
static constexpr int KDIM = 4096;   // D_IN
static constexpr int BM = 128;
static constexpr int BN = 128;
static constexpr int BK = 64;       // int8 elements per K-tile (64 bytes/row)

// Async global->LDS, 16B per lane. LDS dest is wave-uniform base; HW writes
// lane i at base + i*16. AS casts go through integers (generic LDS pointer's
// low 32 bits are the LDS offset; generic global pointer == AS1 address).
__device__ __forceinline__ void lds_load16(const void* gptr, void* lptr) {
    __builtin_amdgcn_global_load_lds(
        (const __attribute__((address_space(1))) void*)(uintptr_t)gptr,
        (__attribute__((address_space(3))) void*)(uint32_t)(uintptr_t)lptr,
        16, 0, 0);
}

// x fp32 -> int8 (round-to-nearest-even like jnp.round, clip to [-128,127]),
// 4 elems/thread: float4 in, packed int out.
__global__ __launch_bounds__(256) void quant_x_k(const float4* __restrict__ x,
                                                 int* __restrict__ xq,
                                                 const float* __restrict__ s_in) {
    const int i = blockIdx.x * 256 + threadIdx.x;
    const float s = s_in[0];
    float4 v = x[i];
    const int q0 = (int)fminf(fmaxf(__builtin_rintf(v.x / s), -128.0f), 127.0f);
    const int q1 = (int)fminf(fmaxf(__builtin_rintf(v.y / s), -128.0f), 127.0f);
    const int q2 = (int)fminf(fmaxf(__builtin_rintf(v.z / s), -128.0f), 127.0f);
    const int q3 = (int)fminf(fmaxf(__builtin_rintf(v.w / s), -128.0f), 127.0f);
    xq[i] = (q0 & 0xff) | ((q1 & 0xff) << 8) | ((q2 & 0xff) << 16) | ((q3 & 0xff) << 24);
}

// weight int32 -> int8 pack, 4 elems/thread.
__global__ __launch_bounds__(256) void pack_w_k(const int4* __restrict__ w,
                                                int* __restrict__ wq) {
    const int i = blockIdx.x * 256 + threadIdx.x;
    int4 v = w[i];
    wq[i] = (v.x & 0xff) | ((v.y & 0xff) << 8) | ((v.z & 0xff) << 16) | ((v.w & 0xff) << 24);
}

// C[m][n] = (sum_k A[m][k] * Bt[n][k]) * fscale
// A: MDIM x KDIM int8 row-major (quantized x), Bt: NDIM x KDIM int8 row-major.
// 128x128 tile / block of 256 threads; 4 waves in 2x2, each wave 64x64 via
// 4x4 grid of mfma_i32_16x16x64_i8. Single LDS buffer, 2-barrier K-loop,
// global_load_lds width-16 staging (m97 structure).
__global__ __launch_bounds__(256) void gemm_i8_k(const int8_t* __restrict__ A,
                                                 const int8_t* __restrict__ Bt,
                                                 float* __restrict__ C,
                                                 const float* __restrict__ w_scale,
                                                 const float* __restrict__ in_scale) {
    __shared__ int8_t sA[BM * BK];   // 8 KB: 128 rows x 64 bytes
    __shared__ int8_t sB[BN * BK];   // 8 KB

    const int tid  = threadIdx.x;
    const int lane = tid & 63;
    const int wave = tid >> 6;
    const int bm = blockIdx.y;
    const int bn = blockIdx.x;

    const int wm = (wave >> 1) * 64;   // wave's row offset in tile
    const int wn = (wave & 1) * 64;    // wave's col offset in tile
    const int lm = lane & 15;          // row within 16x16 fragment
    const int kq = (lane >> 4) * 16;   // lane-group's 16-byte K-chunk offset

    v4i acc[4][4] = {};

    // Staging: thread tid copies chunk tid (rows 0..63) and tid+256 (rows 64..127).
    const int srow = tid >> 2;               // 0..63
    const int scol = (tid & 3) * 16;         // 0/16/32/48 within the 64B row
    const int8_t* gA0 = A  + (size_t)(bm * BM + srow) * KDIM + scol;
    const int8_t* gB0 = Bt + (size_t)(bn * BN + srow) * KDIM + scol;
    const size_t half = (size_t)64 * KDIM;   // +64 rows in global
    int8_t* lA0 = sA + wave * 1024;          // wave-uniform LDS bases
    int8_t* lA1 = sA + 4096 + wave * 1024;
    int8_t* lB0 = sB + wave * 1024;
    int8_t* lB1 = sB + 4096 + wave * 1024;

    // Fragment LDS offsets (loop-invariant).
    int aoff[4], boff[4];
#pragma unroll
    for (int t = 0; t < 4; ++t) {
        aoff[t] = (wm + t * 16 + lm) * BK + kq;
        boff[t] = (wn + t * 16 + lm) * BK + kq;
    }

    for (int k0 = 0; k0 < KDIM; k0 += BK) {
        __syncthreads();                     // previous iter's ds_reads done
        lds_load16(gA0 + k0,        lA0);
        lds_load16(gA0 + half + k0, lA1);
        lds_load16(gB0 + k0,        lB0);
        lds_load16(gB0 + half + k0, lB1);
        __syncthreads();                     // vmcnt(0) drain: staging visible

        v4i av[4], bv[4];
#pragma unroll
        for (int t = 0; t < 4; ++t) {
            av[t] = *(const v4i*)(sA + aoff[t]);
            bv[t] = *(const v4i*)(sB + boff[t]);
        }
#pragma unroll
        for (int mt = 0; mt < 4; ++mt)
#pragma unroll
            for (int nt = 0; nt < 4; ++nt)
                acc[mt][nt] = __builtin_amdgcn_mfma_i32_16x16x64_i8(
                    av[mt], bv[nt], acc[mt][nt], 0, 0, 0);
    }

    // Epilogue: D layout col = lane&15 (n), row = (lane>>4)*4 + reg (m).
    const float fs = w_scale[0] * in_scale[0];
    const int crow = (lane >> 4) * 4;
#pragma unroll
    for (int mt = 0; mt < 4; ++mt) {
#pragma unroll
        for (int nt = 0; nt < 4; ++nt) {
            const size_t n = (size_t)bn * BN + wn + nt * 16 + lm;
            const size_t mb = (size_t)bm * BM + wm + mt * 16 + crow;
#pragma unroll
            for (int r = 0; r < 4; ++r) {
                C[(mb + r) * NDIM + n] = (float)acc[mt][nt][r] * fs;
            }
        }
    }
}

extern "C" void kernel_launch(void* const* d_in, const int* in_sizes, int n_in,
                              void* d_out, int out_size, void* d_ws, size_t ws_size,
                              hipStream_t stream) {
    const float* x        = (const float*)d_in[0];
    const int*   w        = (const int*)d_in[1];
    const float* w_scale  = (const float*)d_in[2];
    const float* in_scale = (const float*)d_in[3];
    float* out = (float*)d_out;

    int8_t* xq = (int8_t*)d_ws;                       // 33,554,432 B
    int8_t* wq = xq + (size_t)MDIM * KDIM;            // 16,777,216 B (total 48 MB)

    quant_x_k<<<(MDIM * KDIM / 4) / 256, 256, 0, stream>>>(
        (const float4*)x, (int*)xq, in_scale);
    pack_w_k<<<(NDIM * KDIM / 4) / 256, 256, 0, stream>>>(
        (const int4*)w, (int*)wq);

    dim3 grid(NDIM / BN, MDIM / BM);                  // (32, 64)
    gemm_i8_k<<<grid, 256, 0, stream>>>(xq, wq, out, w_scale, in_scale);
}

// Round 2
// 389.274 us; speedup vs baseline: 1.0611x; 1.0611x over previous
//
#include <hip/hip_runtime.h>
#include <stdint.h>

typedef int v4i __attribute__((ext_vector_type(4)));

static constexpr int MDIM = 8192;   // B * S
static constexpr int NDIM = 4096;   // D_OUT
static constexpr int KDIM = 4096;   // D_IN
static constexpr int BM = 128;
static constexpr int BN = 128;
static constexpr int BK = 128;      // int8 elements (=bytes) per K-tile row

static constexpr int QBLOCKS = (MDIM * KDIM / 16) / 256;  // 8192
static constexpr int WBLOCKS = (NDIM * KDIM / 16) / 256;  // 4096

// Async global->LDS, 16B per lane: HW writes lane i at (wave-uniform base) + i*16.
__device__ __forceinline__ void lds_load16(const void* gptr, void* lptr) {
    __builtin_amdgcn_global_load_lds(
        (const __attribute__((address_space(1))) void*)(uintptr_t)gptr,
        (__attribute__((address_space(3))) void*)(uint32_t)(uintptr_t)lptr,
        16, 0, 0);
}

__device__ __forceinline__ int q1(float f, float s) {
    // matches jnp: round-half-even(x / s) clipped to int8 range
    return (int)fminf(fmaxf(__builtin_rintf(f / s), -128.0f), 127.0f);
}
__device__ __forceinline__ int pack4(int a, int b, int c, int d) {
    return (a & 0xff) | ((b & 0xff) << 8) | ((c & 0xff) << 16) | ((d & 0xff) << 24);
}

// Fused prep: blocks [0,QBLOCKS) quantize x (fp32 -> int8), blocks
// [QBLOCKS, QBLOCKS+WBLOCKS) pack w (int32 -> int8). 16 elems/thread,
// 64 B loads + 16 B stores. Block-uniform branch, no divergence.
__global__ __launch_bounds__(256) void prep_k(const float4* __restrict__ x,
                                              int4* __restrict__ xq,
                                              const int4* __restrict__ w,
                                              int4* __restrict__ wq,
                                              const float* __restrict__ s_in) {
    const int b = blockIdx.x;
    if (b < QBLOCKS) {
        const int i = b * 256 + threadIdx.x;
        const float s = s_in[0];
        const float4 v0 = x[4 * i + 0];
        const float4 v1 = x[4 * i + 1];
        const float4 v2 = x[4 * i + 2];
        const float4 v3 = x[4 * i + 3];
        int4 o;
        o.x = pack4(q1(v0.x, s), q1(v0.y, s), q1(v0.z, s), q1(v0.w, s));
        o.y = pack4(q1(v1.x, s), q1(v1.y, s), q1(v1.z, s), q1(v1.w, s));
        o.z = pack4(q1(v2.x, s), q1(v2.y, s), q1(v2.z, s), q1(v2.w, s));
        o.w = pack4(q1(v3.x, s), q1(v3.y, s), q1(v3.z, s), q1(v3.w, s));
        xq[i] = o;
    } else {
        const int i = (b - QBLOCKS) * 256 + threadIdx.x;
        const int4 a = w[4 * i + 0];
        const int4 c = w[4 * i + 1];
        const int4 d = w[4 * i + 2];
        const int4 e = w[4 * i + 3];
        int4 o;
        o.x = pack4(a.x, a.y, a.z, a.w);
        o.y = pack4(c.x, c.y, c.z, c.w);
        o.z = pack4(d.x, d.y, d.z, d.w);
        o.w = pack4(e.x, e.y, e.z, e.w);
        wq[i] = o;
    }
}

// C[m][n] = (sum_k A[m][k]*Bt[n][k]) * fscale. 128x128 tile, BK=128.
// LDS layout XOR-swizzled: chunk c (16 B) of row r lives at slot (c ^ (r&7)).
// Staging realizes the swizzle by permuting the *global source* per lane
// (LDS side of global_load_lds is fixed: base + lane*16).
// Fragment ds_read_b128: addr = row*128 + ((ks*4+q)^(row&7))*16 — every
// consecutive-8-lane phase covers all 32 banks => conflict-free.
__global__ __launch_bounds__(256) void gemm_i8_k(const int8_t* __restrict__ A,
                                                 const int8_t* __restrict__ Bt,
                                                 float* __restrict__ C,
                                                 const float* __restrict__ w_scale,
                                                 const float* __restrict__ in_scale) {
    __shared__ int8_t sA[BM * BK];   // 16 KB
    __shared__ int8_t sB[BN * BK];   // 16 KB

    const int tid  = threadIdx.x;
    const int lane = tid & 63;
    const int wave = tid >> 6;
    const int bm = blockIdx.y;
    const int bn = blockIdx.x;

    const int wm = (wave >> 1) * 64;   // wave row offset in tile
    const int wn = (wave & 1) * 64;    // wave col offset in tile
    const int lm = lane & 15;          // fragment row
    const int q  = lane >> 4;          // K-quarter (16 B chunk within 64)

    v4i acc[4][4] = {};

    // Staging geometry: call j (j=0..3 per array per wave) covers rows
    // r = wave*32 + j*8 + (lane>>3); lane supplies global chunk
    // c = (lane&7) ^ (lane>>3) into LDS slot (lane&7) of its row.
    const int rr = wave * 32 + (lane >> 3);
    const int cc = ((lane & 7) ^ (lane >> 3)) * 16;
    const int8_t* gA0 = A  + (size_t)(bm * BM + rr) * KDIM + cc;
    const int8_t* gB0 = Bt + (size_t)(bn * BN + rr) * KDIM + cc;
    int8_t* lA0 = sA + wave * 4096;
    int8_t* lB0 = sB + wave * 4096;

    // Fragment LDS offsets; row&7 == lm&7 since wm, t*16 are multiples of 8.
    int aoff[2][4], boff[2][4];
#pragma unroll
    for (int ks = 0; ks < 2; ++ks)
#pragma unroll
        for (int t = 0; t < 4; ++t) {
            const int sw = (((ks * 4 + q) ^ (lm & 7)) << 4);
            aoff[ks][t] = (wm + t * 16 + lm) * BK + sw;
            boff[ks][t] = (wn + t * 16 + lm) * BK + sw;
        }

    for (int k0 = 0; k0 < KDIM; k0 += BK) {
        __syncthreads();                     // previous iter's ds_reads done
#pragma unroll
        for (int j = 0; j < 4; ++j) {
            lds_load16(gA0 + k0 + (size_t)j * (8 * KDIM), lA0 + j * 1024);
            lds_load16(gB0 + k0 + (size_t)j * (8 * KDIM), lB0 + j * 1024);
        }
        __syncthreads();                     // staging visible

#pragma unroll
        for (int ks = 0; ks < 2; ++ks) {
            v4i av[4], bv[4];
#pragma unroll
            for (int t = 0; t < 4; ++t) {
                av[t] = *(const v4i*)(sA + aoff[ks][t]);
                bv[t] = *(const v4i*)(sB + boff[ks][t]);
            }
#pragma unroll
            for (int mt = 0; mt < 4; ++mt)
#pragma unroll
                for (int nt = 0; nt < 4; ++nt)
                    acc[mt][nt] = __builtin_amdgcn_mfma_i32_16x16x64_i8(
                        av[mt], bv[nt], acc[mt][nt], 0, 0, 0);
        }
    }

    // Epilogue: D layout col = lane&15 (n), row = (lane>>4)*4 + reg (m).
    const float fs = w_scale[0] * in_scale[0];
    const int crow = q * 4;
#pragma unroll
    for (int mt = 0; mt < 4; ++mt) {
#pragma unroll
        for (int nt = 0; nt < 4; ++nt) {
            const size_t n  = (size_t)bn * BN + wn + nt * 16 + lm;
            const size_t mb = (size_t)bm * BM + wm + mt * 16 + crow;
#pragma unroll
            for (int r = 0; r < 4; ++r) {
                C[(mb + r) * NDIM + n] = (float)acc[mt][nt][r] * fs;
            }
        }
    }
}

extern "C" void kernel_launch(void* const* d_in, const int* in_sizes, int n_in,
                              void* d_out, int out_size, void* d_ws, size_t ws_size,
                              hipStream_t stream) {
    const float* x        = (const float*)d_in[0];
    const int*   w        = (const int*)d_in[1];
    const float* w_scale  = (const float*)d_in[2];
    const float* in_scale = (const float*)d_in[3];
    float* out = (float*)d_out;

    int8_t* xq = (int8_t*)d_ws;                       // 33,554,432 B
    int8_t* wq = xq + (size_t)MDIM * KDIM;            // 16,777,216 B (48 MB total)

    prep_k<<<QBLOCKS + WBLOCKS, 256, 0, stream>>>(
        (const float4*)x, (int4*)xq, (const int4*)w, (int4*)wq, in_scale);

    dim3 grid(NDIM / BN, MDIM / BM);                  // (32, 64)
    gemm_i8_k<<<grid, 256, 0, stream>>>(xq, wq, out, w_scale, in_scale);
}